// Round 4
// baseline (425.494 us; speedup 1.0000x reference)
//
#include <hip/hip_runtime.h>
#include <hip/hip_bf16.h>
#include <stdint.h>

#define Bsz 512
#define Ssz 64
#define Esz 768
#define Dsz 256
#define MROWS (Bsz * Ssz)   // 32768
#define FIN 1024

typedef _Float16 f16;
typedef f16 f16x4 __attribute__((ext_vector_type(4)));
typedef f16 f16x8v __attribute__((ext_vector_type(8)));
typedef float f32x4 __attribute__((ext_vector_type(4)));

// async 16B/lane global->LDS copy. LDS dest = wave-uniform base + lane*16.
__device__ __forceinline__ void async_copy16(const void* g, void* l) {
    __builtin_amdgcn_global_load_lds((const __attribute__((address_space(1))) uint32_t*)g,
                                     (__attribute__((address_space(3))) uint32_t*)l, 16, 0, 0);
}

// ---------------------------------------------------------------------------
// prep: Wp (3x[256][768] f32) -> f16; corr [256][256] f32 -> corrT f16 [e][d];
//       Wb [64][1024] f32 -> f16 (for the G GEMMs)
__global__ __launch_bounds__(256) void prep(const float* __restrict__ Wp0,
                                            const float* __restrict__ Wp1,
                                            const float* __restrict__ Wp2,
                                            const float* __restrict__ corr,
                                            const float* __restrict__ Wb,
                                            f16* __restrict__ Wph,
                                            f16* __restrict__ corrT,
                                            f16* __restrict__ Wbh) {
    const int t = blockIdx.x * 256 + threadIdx.x;
    if (t < 3 * 196608) {
        const int z = t / 196608, i = t % 196608;
        const float* W = (z == 0) ? Wp0 : (z == 1) ? Wp1 : Wp2;
        Wph[(size_t)z * 196608 + i] = (f16)W[i];
    }
    if (t < 65536) {
        const int d = t >> 8, e = t & 255;
        corrT[e * 256 + d] = (f16)corr[d * 256 + e];
        Wbh[t] = (f16)Wb[t];
    }
}

// ---------------------------------------------------------------------------
// MFMA GEMM: C[m,n] = sum_k A[m,k] * B[n,k]  (B given [N][K] row-major, f16)
// Output f16 [M][256]. Tile 128x128xBK64, 256 threads = 4 waves, wave 64x64.
// T3 minimal 2-phase double-buffer: per iter, issue next tile's
// global_load_lds FIRST, then compute current tile, then one barrier (its
// vmcnt(0) drain waits only latency-minus-compute). Loads stay in flight
// during the whole compute phase; VMEM queue never empties -> BW-bound.
// No registers near barriers (pure global_load_lds staging).
// Swizzle (same involution on stage-source and fragment-read):
//   A_F32: unit(row,c) at row*16 + (c ^ (row&15)), c = k/4 (0..15), 2048 units/buf
//   f16:   unit(row,u) at row*8  + (u ^ (row&7)),  u = k/8 (0..7),  1024 units/buf
template <bool A_F16, bool BIAS>
__global__ __launch_bounds__(256) void mfma_gemm(
    const float* __restrict__ A32a, const float* __restrict__ A32b,
    const float* __restrict__ A32c, const f16* __restrict__ A16,
    const f16* __restrict__ Bh, const float* __restrict__ biasA,
    const float* __restrict__ biasB, const float* __restrict__ biasC,
    f16* __restrict__ Ch, int K) {
    constexpr int ABYTES = A_F16 ? 16384 : 32768;  // A tile bytes per buffer
    constexpr int BUF = ABYTES + 16384;            // + B tile (16 KB)
    __shared__ __align__(16) char smem[2 * BUF];   // 96 KB (A f32) / 64 KB (A f16)

    const int tid = threadIdx.x;
    const int n0 = blockIdx.x * 128;
    const int m0 = blockIdx.y * 128;
    const int z = blockIdx.z;
    const float* A32 = (z == 0) ? A32a : (z == 1) ? A32b : A32c;
    const float* bias = (z == 0) ? biasA : (z == 1) ? biasB : biasC;
    const f16* Bz = Bh + (size_t)z * 256 * K;
    f16* Cz = Ch + (size_t)z * MROWS * 256;

    const int lane = tid & 63;
    const int w = tid >> 6;
    const int lr = lane & 15;
    const int lk = lane >> 4;
    const int ma = (w >> 1) * 4;  // wave's first m-sub (of 8)
    const int nb = (w & 1) * 4;   // wave's first n-sub (of 8)

    f32x4 acc[4][4];
#pragma unroll
    for (int i = 0; i < 4; i++)
#pragma unroll
        for (int j = 0; j < 4; j++) acc[i][j] = (f32x4){0.f, 0.f, 0.f, 0.f};

    auto stage = [&](int buf, int k0) {
        char* base = smem + buf * BUF;
        // A tile
#pragma unroll
        for (int i = 0; i < (A_F16 ? 4 : 8); i++) {
            const int Ub = (w * (A_F16 ? 4 : 8) + i) * 64;
            const int U = Ub + lane;
            if constexpr (A_F16) {
                const int row = U >> 3, u = (U & 7) ^ (row & 7);
                async_copy16(A16 + (size_t)(m0 + row) * K + k0 + u * 8, base + Ub * 16);
            } else {
                const int row = U >> 4, c = (U & 15) ^ (row & 15);
                async_copy16(A32 + (size_t)(m0 + row) * K + k0 + c * 4, base + Ub * 16);
            }
        }
        // B tile
#pragma unroll
        for (int i = 0; i < 4; i++) {
            const int Ub = (w * 4 + i) * 64;
            const int U = Ub + lane;
            const int row = U >> 3, u = (U & 7) ^ (row & 7);
            async_copy16(Bz + (size_t)(n0 + row) * K + k0 + u * 8, base + ABYTES + Ub * 16);
        }
    };

    stage(0, 0);
    __syncthreads();  // vmcnt(0) drain: tile 0 staged
    int cur = 0;
    const int NT = K >> 6;
    for (int t = 0; t < NT; t++) {
        if (t + 1 < NT) stage(cur ^ 1, (t + 1) << 6);  // in flight during compute
        __builtin_amdgcn_sched_barrier(0);             // keep load-issue ahead of compute
        const char* base = smem + cur * BUF;
        const f16* Af16L = (const f16*)base;
        const float* Af32L = (const float*)base;
        const f16* BfL = (const f16*)(base + ABYTES);
#pragma unroll
        for (int kh = 0; kh < 2; kh++) {
            f16x8v af[4], bf[4];
#pragma unroll
            for (int i = 0; i < 4; i++) {
                const int row = (ma + i) * 16 + lr;  // row&15 == lr
                if constexpr (A_F16) {
                    const int u = (kh * 4 + lk) ^ (row & 7);
                    af[i] = *(const f16x8v*)&Af16L[(row * 8 + u) * 8];
                } else {
                    const int c = kh * 8 + lk * 2;
                    const float4 v1 = *(const float4*)&Af32L[(row * 16 + (c ^ lr)) * 4];
                    const float4 v2 = *(const float4*)&Af32L[(row * 16 + ((c + 1) ^ lr)) * 4];
                    f16x8v h;
                    h[0] = (f16)v1.x; h[1] = (f16)v1.y; h[2] = (f16)v1.z; h[3] = (f16)v1.w;
                    h[4] = (f16)v2.x; h[5] = (f16)v2.y; h[6] = (f16)v2.z; h[7] = (f16)v2.w;
                    af[i] = h;
                }
            }
#pragma unroll
            for (int j = 0; j < 4; j++) {
                const int row = (nb + j) * 16 + lr;
                const int u = (kh * 4 + lk) ^ (row & 7);
                bf[j] = *(const f16x8v*)&BfL[(row * 8 + u) * 8];
            }
#pragma unroll
            for (int i = 0; i < 4; i++)
#pragma unroll
                for (int j = 0; j < 4; j++)
                    acc[i][j] = __builtin_amdgcn_mfma_f32_16x16x32_f16(af[i], bf[j], acc[i][j], 0, 0, 0);
        }
        __syncthreads();  // drains next-tile loads (already ~compute-time old) + lgkm
        cur ^= 1;
    }

    // epilogue through LDS for coalesced stores. 128x128 f16 = 32 KB.
    f16* Ce = (f16*)smem;
    const int cr = lane & 15, qr = lane >> 4;
    const int mwl = (w >> 1) * 64;
    const int nwl = (w & 1) * 64;
#pragma unroll
    for (int i = 0; i < 4; i++) {
#pragma unroll
        for (int j = 0; j < 4; j++) {
            const int col = nwl + j * 16 + cr;
            const float bv = BIAS ? bias[n0 + col] : 0.f;
#pragma unroll
            for (int r = 0; r < 4; r++) {
                const int row = mwl + i * 16 + qr * 4 + r;
                Ce[row * 128 + col] = (f16)(acc[i][j][r] + bv);
            }
        }
    }
    __syncthreads();
#pragma unroll
    for (int r = 0; r < 8; r++) {
        const int f = r * 256 + tid;
        const int row = f >> 4, c16 = f & 15;
        uint4 v = *(const uint4*)&Ce[row * 128 + c16 * 8];
        *(uint4*)(Cz + (size_t)(m0 + row) * 256 + n0 + c16 * 8) = v;
    }
}

// ---------------------------------------------------------------------------
// Per (b,q): cc[i,j] = sum_e ac[b,i,e]*other[b,j,e] via MFMA (f16 in, f32 acc),
// fragments read directly from global. Then both softmaxes, wave-parallel:
// 4-way partial max/sum per row & column (16-iter loops, all 256 threads),
// online combine (sum rescaled by exp(pm - M)), then coalesced f16 writes.
// Outputs (f16): aT[q][b][j][i] = softmax_i(cc)[i,j]  (transposed!)
//                oP[q][b][i][j] = softmax_j(cc)[i,j]  (row-major)
__global__ __launch_bounds__(256) void cc_softmax(const f16* __restrict__ ac,
                                                  const f16* __restrict__ proj1,
                                                  const f16* __restrict__ proj2,
                                                  f16* __restrict__ aT,
                                                  f16* __restrict__ oP) {
    const int b = blockIdx.x, q = blockIdx.y;
    const f16* __restrict__ A = ac + (size_t)b * Ssz * Dsz;
    const f16* __restrict__ Bp = (q ? proj2 : proj1) + (size_t)b * Ssz * Dsz;
    __shared__ float sc[64][65];
    __shared__ float pm[4][64], ps[4][64], qm[4][64], qs[4][64];
    __shared__ float CM[64], CI[64], RM[64], RI[64];
    const int tid = threadIdx.x;
    const int lane = tid & 63, w = tid >> 6;
    const int lr = lane & 15;   // row/col within 16-tile (A row, B col)
    const int lk = lane >> 4;   // k-quarter: k = 8*lk + 0..7 within K=32 step

    f32x4 acc[4];
#pragma unroll
    for (int j = 0; j < 4; j++) acc[j] = (f32x4){0.f, 0.f, 0.f, 0.f};

    const f16* __restrict__ Arow = A + (size_t)(w * 16 + lr) * Dsz + lk * 8;
    for (int ks = 0; ks < 8; ks++) {  // K=256 in steps of 32
        f16x8v af = *(const f16x8v*)(Arow + ks * 32);
        f16x8v bf[4];
#pragma unroll
        for (int j = 0; j < 4; j++)
            bf[j] = *(const f16x8v*)(Bp + (size_t)(j * 16 + lr) * Dsz + ks * 32 + lk * 8);
#pragma unroll
        for (int j = 0; j < 4; j++)
            acc[j] = __builtin_amdgcn_mfma_f32_16x16x32_f16(af, bf[j], acc[j], 0, 0, 0);
    }
    // C/D layout: col = lane&15, row = (lane>>4)*4 + r
#pragma unroll
    for (int j = 0; j < 4; j++)
#pragma unroll
        for (int r = 0; r < 4; r++) sc[w * 16 + lk * 4 + r][j * 16 + lr] = acc[j][r];
    __syncthreads();

    const int lid = tid & 63, qa = tid >> 6;
    float m1 = -1e30f, m2 = -1e30f;
#pragma unroll
    for (int it = 0; it < 16; it++) {
        m1 = fmaxf(m1, sc[qa * 16 + it][lid]);  // column lid (reduce over i)
        m2 = fmaxf(m2, sc[lid][qa * 16 + it]);  // row lid (reduce over j)
    }
    float s1 = 0.f, s2 = 0.f;
#pragma unroll
    for (int it = 0; it < 16; it++) {
        s1 += __expf(sc[qa * 16 + it][lid] - m1);
        s2 += __expf(sc[lid][qa * 16 + it] - m2);
    }
    pm[qa][lid] = m1; ps[qa][lid] = s1;
    qm[qa][lid] = m2; qs[qa][lid] = s2;
    __syncthreads();
    if (tid < 128) {
        const int x = tid & 63;
        const bool col = tid < 64;
        float M = -1e30f;
#pragma unroll
        for (int u = 0; u < 4; u++) M = fmaxf(M, col ? pm[u][x] : qm[u][x]);
        float S = 0.f;
#pragma unroll
        for (int u = 0; u < 4; u++)
            S += (col ? ps[u][x] : qs[u][x]) * __expf((col ? pm[u][x] : qm[u][x]) - M);
        if (col) { CM[x] = M; CI[x] = 1.f / S; }
        else     { RM[x] = M; RI[x] = 1.f / S; }
    }
    __syncthreads();
    f16* __restrict__ apT = aT + (size_t)(q * Bsz + b) * 4096;
    f16* __restrict__ opR = oP + (size_t)(q * Bsz + b) * 4096;
#pragma unroll
    for (int it = 0; it < 16; it++) {
        const int i = qa * 16 + it;
        opR[i * 64 + lid] = (f16)(__expf(sc[i][lid] - RM[i]) * RI[i]);
        apT[i * 64 + lid] = (f16)(__expf(sc[lid][i] - CM[i]) * CI[i]);
    }
}

// ---------------------------------------------------------------------------
// Fused tail: G GEMMs + attention contraction + bias + LayerNorm + ReLU.
// Phase G: wave w computes term w: G_w[o][t] = sum_d Wchunk[o,d]*X[t,d]
//   (term = q*2+part; part0: X=anchor(proj0); part1: X=other_q(proj1/2);
//    Wchunk = Wbh[:, q*512+part*256 : +256]) -> swizzled LDS (no global G).
// Phase LN: h[b,s,o] = sum_term( sum_k A_term[s,k]*G_term[o,k] + G_term[o,s] ) + bb[o]
//   term0: A=aT(q0); term1: A=oP(q0); term2: A=aT(q1); term3: A=oP(q1)
// Wave w owns rows s in [16w,16w+16) x all 64 o; LN via 16-lane shfl reduce.
// Gs swizzle: element (o,t) at unit su = o*8 + ((t>>3) ^ (o&7)), offset t&7.
__global__ __launch_bounds__(256) void fused_tail(const f16* __restrict__ proj,
                                                  const f16* __restrict__ Wbh,
                                                  const f16* __restrict__ aT,
                                                  const f16* __restrict__ oP,
                                                  const float* __restrict__ bb,
                                                  const float* __restrict__ gamma,
                                                  const float* __restrict__ beta,
                                                  float* __restrict__ out) {
    const int b = blockIdx.x;
    const int tid = threadIdx.x, lane = tid & 63, w = tid >> 6;
    const int lr = lane & 15, lk = lane >> 4;

    __shared__ __align__(16) f16 Gs[4][4096];

    // ---- G phase: wave w computes its term, K=256, direct-global fragments
    {
        const int q = w >> 1, part = w & 1;
        const int z = part ? (1 + q) : 0;
        const f16* __restrict__ X = proj + ((size_t)z * MROWS + b * 64) * 256;  // [t][256]
        const f16* __restrict__ Wc = Wbh + q * 512 + part * 256;                // rows stride 1024
        f32x4 gacc[4][4];
#pragma unroll
        for (int i = 0; i < 4; i++)
#pragma unroll
            for (int j = 0; j < 4; j++) gacc[i][j] = (f32x4){0.f, 0.f, 0.f, 0.f};
        for (int ks = 0; ks < 8; ks++) {
            f16x8v af[4], bf[4];
#pragma unroll
            for (int mi = 0; mi < 4; mi++)
                af[mi] = *(const f16x8v*)(Wc + (size_t)(mi * 16 + lr) * FIN + ks * 32 + lk * 8);
#pragma unroll
            for (int nj = 0; nj < 4; nj++)
                bf[nj] = *(const f16x8v*)(X + (size_t)(nj * 16 + lr) * 256 + ks * 32 + lk * 8);
#pragma unroll
            for (int mi = 0; mi < 4; mi++)
#pragma unroll
                for (int nj = 0; nj < 4; nj++)
                    gacc[mi][nj] = __builtin_amdgcn_mfma_f32_16x16x32_f16(af[mi], bf[nj], gacc[mi][nj], 0, 0, 0);
        }
        // scatter into swizzled Gs[w]
#pragma unroll
        for (int mi = 0; mi < 4; mi++)
#pragma unroll
            for (int nj = 0; nj < 4; nj++)
#pragma unroll
                for (int r = 0; r < 4; r++) {
                    const int o = mi * 16 + lk * 4 + r;
                    const int t = nj * 16 + lr;
                    Gs[w][(o * 8 + ((t >> 3) ^ (o & 7))) * 8 + (t & 7)] = (f16)gacc[mi][nj][r];
                }
    }
    __syncthreads();

    // ---- attn + LN phase
    f32x4 acc[4];
#pragma unroll
    for (int j = 0; j < 4; j++) acc[j] = (f32x4){0.f, 0.f, 0.f, 0.f};

#pragma unroll
    for (int term = 0; term < 4; term++) {
        const int q = term >> 1;
        const f16* __restrict__ Abase =
            ((term & 1) ? oP : aT) + ((size_t)(q * Bsz + b)) * 4096;
#pragma unroll
        for (int kh = 0; kh < 2; kh++) {
            f16x8v af = *(const f16x8v*)(Abase + (size_t)(w * 16 + lr) * 64 + kh * 32 + lk * 8);
#pragma unroll
            for (int jf = 0; jf < 4; jf++) {
                const int o = jf * 16 + lr;
                const int su = o * 8 + ((kh * 4 + lk) ^ (o & 7));
                f16x8v bf = *(const f16x8v*)&Gs[term][su * 8];
                acc[jf] = __builtin_amdgcn_mfma_f32_16x16x32_f16(af, bf, acc[jf], 0, 0, 0);
            }
        }
    }

    float bbv[4], gv[4], bv2[4];
#pragma unroll
    for (int jf = 0; jf < 4; jf++) {
        const int o = jf * 16 + lr;
        bbv[jf] = bb[o];
        gv[jf] = gamma[o];
        bv2[jf] = beta[o];
    }
#pragma unroll
    for (int r = 0; r < 4; r++) {
        const int s = w * 16 + lk * 4 + r;
        float h[4];
        float s1 = 0.f, s2 = 0.f;
#pragma unroll
        for (int jf = 0; jf < 4; jf++) {
            const int o = jf * 16 + lr;
            float resid = 0.f;
#pragma unroll
            for (int term = 0; term < 4; term++) {
                const int su = o * 8 + ((s >> 3) ^ (o & 7));
                resid += (float)Gs[term][su * 8 + (s & 7)];
            }
            h[jf] = acc[jf][r] + resid + bbv[jf];
            s1 += h[jf];
            s2 += h[jf] * h[jf];
        }
#pragma unroll
        for (int m = 1; m < 16; m <<= 1) {
            s1 += __shfl_xor(s1, m);
            s2 += __shfl_xor(s2, m);
        }
        const float mu = s1 * (1.f / 64.f);
        const float inv = rsqrtf(s2 * (1.f / 64.f) - mu * mu + 1e-5f);
#pragma unroll
        for (int jf = 0; jf < 4; jf++) {
            const float v = (h[jf] - mu) * inv * gv[jf] + bv2[jf];
            out[(size_t)(b * 64 + s) * 64 + jf * 16 + lr] = fmaxf(v, 0.f);
        }
    }
}

extern "C" void kernel_launch(void* const* d_in, const int* in_sizes, int n_in,
                              void* d_out, int out_size, void* d_ws, size_t ws_size,
                              hipStream_t stream) {
    const float* latent0 = (const float*)d_in[0];
    const float* Wp0 = (const float*)d_in[1];
    const float* bp0 = (const float*)d_in[2];
    const float* latent1 = (const float*)d_in[3];
    const float* Wp1 = (const float*)d_in[4];
    const float* bp1 = (const float*)d_in[5];
    const float* latent2 = (const float*)d_in[6];
    const float* Wp2 = (const float*)d_in[7];
    const float* bp2 = (const float*)d_in[8];
    const float* corr = (const float*)d_in[9];
    const float* Wb = (const float*)d_in[10];
    const float* bb = (const float*)d_in[11];
    const float* gamma = (const float*)d_in[12];
    const float* beta = (const float*)d_in[13];

    char* ws = (char*)d_ws;
    f16* proj_h = (f16*)ws;                               // 3 * 16 MB
    f16* ac_h = (f16*)(ws + 48ull * 1024 * 1024);         // 16 MB
    f16* aT = (f16*)(ws + 64ull * 1024 * 1024);           // 8 MB  [2][512][64][64]
    f16* oP = (f16*)(ws + 72ull * 1024 * 1024);           // 8 MB  [2][512][64][64]
    f16* Wph = (f16*)(ws + 160ull * 1024 * 1024);         // 1.125 MB
    f16* corrT = (f16*)(ws + 162ull * 1024 * 1024);       // 128 KB
    f16* Wbh = (f16*)(ws + 162ull * 1024 * 1024 + 128ull * 1024);  // 128 KB

    float* out = (float*)d_out;
    dim3 blk(256);

    // pre-convert weights
    prep<<<2304, blk, 0, stream>>>(Wp0, Wp1, Wp2, corr, Wb, Wph, corrT, Wbh);

    // projections: proj_h[z] = latent_z @ Wp_z^T + bp_z   (fp16 MFMA, dbuf-pipelined)
    mfma_gemm<false, true><<<dim3(2, 256, 3), blk, 0, stream>>>(
        latent0, latent1, latent2, (const f16*)nullptr, Wph, bp0, bp1, bp2, proj_h, Esz);

    // ac = proj0 @ corr  (B = corrT [e][d] f16)
    mfma_gemm<true, false><<<dim3(2, 256, 1), blk, 0, stream>>>(
        (const float*)nullptr, (const float*)nullptr, (const float*)nullptr, proj_h,
        corrT, (const float*)nullptr, (const float*)nullptr, (const float*)nullptr,
        ac_h, Dsz);

    const f16* proj1_h = proj_h + (size_t)MROWS * 256;
    const f16* proj2_h = proj_h + 2ull * MROWS * 256;

    // cc (MFMA) + both softmaxes -> aT (transposed) and oP (row-major), f16
    cc_softmax<<<dim3(Bsz, 2), blk, 0, stream>>>(ac_h, proj1_h, proj2_h, aT, oP);

    // fused G GEMMs + attention contraction + bias + LayerNorm + ReLU
    fused_tail<<<Bsz, blk, 0, stream>>>(proj_h, Wbh, aT, oP, bb, gamma, beta, out);

    (void)in_sizes; (void)n_in; (void)out_size; (void)ws_size;
}

// Round 5
// 401.123 us; speedup vs baseline: 1.0608x; 1.0608x over previous
//
#include <hip/hip_runtime.h>
#include <hip/hip_bf16.h>
#include <stdint.h>

#define Bsz 512
#define Ssz 64
#define Esz 768
#define Dsz 256
#define MROWS (Bsz * Ssz)   // 32768
#define FIN 1024

typedef _Float16 f16;
typedef f16 f16x4 __attribute__((ext_vector_type(4)));
typedef f16 f16x8v __attribute__((ext_vector_type(8)));
typedef float f32x4 __attribute__((ext_vector_type(4)));

// async 16B/lane global->LDS copy. LDS dest = wave-uniform base + lane*16.
__device__ __forceinline__ void async_copy16(const void* g, void* l) {
    __builtin_amdgcn_global_load_lds((const __attribute__((address_space(1))) uint32_t*)g,
                                     (__attribute__((address_space(3))) uint32_t*)l, 16, 0, 0);
}

// ---------------------------------------------------------------------------
// prep: Wp (3x[256][768] f32) -> f16; corr [256][256] f32 -> corrT f16 [e][d];
//       Wb [64][1024] f32 -> f16 (for the G GEMMs)
__global__ __launch_bounds__(256) void prep(const float* __restrict__ Wp0,
                                            const float* __restrict__ Wp1,
                                            const float* __restrict__ Wp2,
                                            const float* __restrict__ corr,
                                            const float* __restrict__ Wb,
                                            f16* __restrict__ Wph,
                                            f16* __restrict__ corrT,
                                            f16* __restrict__ Wbh) {
    const int t = blockIdx.x * 256 + threadIdx.x;
    if (t < 3 * 196608) {
        const int z = t / 196608, i = t % 196608;
        const float* W = (z == 0) ? Wp0 : (z == 1) ? Wp1 : Wp2;
        Wph[(size_t)z * 196608 + i] = (f16)W[i];
    }
    if (t < 65536) {
        const int d = t >> 8, e = t & 255;
        corrT[e * 256 + d] = (f16)corr[d * 256 + e];
        Wbh[t] = (f16)Wb[t];
    }
}

// ---------------------------------------------------------------------------
// MFMA GEMM: C[m,n] = sum_k A[m,k] * B[n,k]  (B given [N][K] row-major, f16)
// Output f16 [M][256]. Tile 128x128xBK32, 256 threads = 4 waves, wave 64x64.
// T4 counted-vmcnt double-buffer: per iter, issue next tile's global_load_lds,
// then s_waitcnt vmcnt(N) with N = one stage's per-wave inst count (leaves the
// next tile IN FLIGHT), then raw s_barrier (no auto vmcnt(0) drain), compute,
// raw s_barrier. The VMEM queue never empties -> BW-bound, and 48 KB LDS keeps
// 3 blocks/CU of TLP. No registers near barriers (pure global_load_lds).
// Race-freedom: wave's own tile-t loads are its N oldest; vmcnt(N)+barrier =>
// tile t fully in LDS; buffer t is only rewritten after the post-compute
// barrier of the iter that last read it.
// Swizzle (same involution on stage-source and fragment-read):
//   A_F32: unit(row,c) at row*8 + (c ^ (row&7)), c = k/4 (0..7), 1024 units/buf
//   f16:   unit(row,u) at row*4 + (u ^ (row&3)), u = k/8 (0..3),  512 units/buf
template <bool A_F16, bool BIAS>
__global__ __launch_bounds__(256) void mfma_gemm(
    const float* __restrict__ A32a, const float* __restrict__ A32b,
    const float* __restrict__ A32c, const f16* __restrict__ A16,
    const f16* __restrict__ Bh, const float* __restrict__ biasA,
    const float* __restrict__ biasB, const float* __restrict__ biasC,
    f16* __restrict__ Ch, int K) {
    constexpr int ABYTES = A_F16 ? 8192 : 16384;  // A tile bytes per buffer
    constexpr int BUF = ABYTES + 8192;            // + B tile (8 KB)
    __shared__ __align__(16) char smem[2 * BUF];  // 48 KB (A f32) / 32 KB (A f16)

    const int tid = threadIdx.x;
    const int n0 = blockIdx.x * 128;
    const int m0 = blockIdx.y * 128;
    const int z = blockIdx.z;
    const float* A32 = (z == 0) ? A32a : (z == 1) ? A32b : A32c;
    const float* bias = (z == 0) ? biasA : (z == 1) ? biasB : biasC;
    const f16* Bz = Bh + (size_t)z * 256 * K;
    f16* Cz = Ch + (size_t)z * MROWS * 256;

    const int lane = tid & 63;
    const int w = tid >> 6;
    const int lr = lane & 15;
    const int lk = lane >> 4;
    const int ma = (w >> 1) * 4;  // wave's first m-sub (of 8)
    const int nb = (w & 1) * 4;   // wave's first n-sub (of 8)

    f32x4 acc[4][4];
#pragma unroll
    for (int i = 0; i < 4; i++)
#pragma unroll
        for (int j = 0; j < 4; j++) acc[i][j] = (f32x4){0.f, 0.f, 0.f, 0.f};

    auto stage = [&](int buf, int k0) {
        char* base = smem + buf * BUF;
        // A tile (f32: 1024 units, 4 insts/wave; f16: 512 units, 2 insts/wave)
#pragma unroll
        for (int i = 0; i < (A_F16 ? 2 : 4); i++) {
            const int Ub = (w * (A_F16 ? 2 : 4) + i) * 64;
            const int U = Ub + lane;
            if constexpr (A_F16) {
                const int row = U >> 2, u = (U & 3) ^ (row & 3);
                async_copy16(A16 + (size_t)(m0 + row) * K + k0 + u * 8, base + Ub * 16);
            } else {
                const int row = U >> 3, c = (U & 7) ^ (row & 7);
                async_copy16(A32 + (size_t)(m0 + row) * K + k0 + c * 4, base + Ub * 16);
            }
        }
        // B tile (512 units, 2 insts/wave)
#pragma unroll
        for (int i = 0; i < 2; i++) {
            const int Ub = (w * 2 + i) * 64;
            const int U = Ub + lane;
            const int row = U >> 2, u = (U & 3) ^ (row & 3);
            async_copy16(Bz + (size_t)(n0 + row) * K + k0 + u * 8, base + ABYTES + Ub * 16);
        }
    };

    stage(0, 0);
    int cur = 0;
    const int NT = K >> 5;
    for (int t = 0; t < NT; t++) {
        if (t + 1 < NT) {
            stage(cur ^ 1, (t + 1) << 5);  // next tile: stays in flight through compute
            if constexpr (A_F16) {
                asm volatile("s_waitcnt vmcnt(4)" ::: "memory");  // tile t done, t+1 in flight
            } else {
                asm volatile("s_waitcnt vmcnt(6)" ::: "memory");
            }
        } else {
            asm volatile("s_waitcnt vmcnt(0)" ::: "memory");
        }
        __builtin_amdgcn_sched_barrier(0);
        asm volatile("s_barrier" ::: "memory");  // raw: no vmcnt(0) auto-drain
        __builtin_amdgcn_sched_barrier(0);

        const char* base = smem + cur * BUF;
        const f16* Af16L = (const f16*)base;
        const float* Af32L = (const float*)base;
        const f16* BfL = (const f16*)(base + ABYTES);
        f16x8v af[4], bf[4];
#pragma unroll
        for (int i = 0; i < 4; i++) {
            const int row = (ma + i) * 16 + lr;
            if constexpr (A_F16) {
                const int u = lk ^ (row & 3);
                af[i] = *(const f16x8v*)&Af16L[(row * 4 + u) * 8];
            } else {
                const int c0 = (2 * lk) ^ (row & 7);
                const int c1 = (2 * lk + 1) ^ (row & 7);
                const float4 v1 = *(const float4*)&Af32L[(row * 8 + c0) * 4];
                const float4 v2 = *(const float4*)&Af32L[(row * 8 + c1) * 4];
                f16x8v h;
                h[0] = (f16)v1.x; h[1] = (f16)v1.y; h[2] = (f16)v1.z; h[3] = (f16)v1.w;
                h[4] = (f16)v2.x; h[5] = (f16)v2.y; h[6] = (f16)v2.z; h[7] = (f16)v2.w;
                af[i] = h;
            }
        }
#pragma unroll
        for (int j = 0; j < 4; j++) {
            const int row = (nb + j) * 16 + lr;
            const int u = lk ^ (row & 3);
            bf[j] = *(const f16x8v*)&BfL[(row * 4 + u) * 8];
        }
#pragma unroll
        for (int i = 0; i < 4; i++)
#pragma unroll
            for (int j = 0; j < 4; j++)
                acc[i][j] = __builtin_amdgcn_mfma_f32_16x16x32_f16(af[i], bf[j], acc[i][j], 0, 0, 0);

        __builtin_amdgcn_sched_barrier(0);
        asm volatile("s_barrier" ::: "memory");  // all waves done reading buf cur
        cur ^= 1;
    }

    // epilogue through LDS for coalesced stores. 128x128 f16 = 32 KB.
    f16* Ce = (f16*)smem;
    const int cr = lane & 15, qr = lane >> 4;
    const int mwl = (w >> 1) * 64;
    const int nwl = (w & 1) * 64;
#pragma unroll
    for (int i = 0; i < 4; i++) {
#pragma unroll
        for (int j = 0; j < 4; j++) {
            const int col = nwl + j * 16 + cr;
            const float bv = BIAS ? bias[n0 + col] : 0.f;
#pragma unroll
            for (int r = 0; r < 4; r++) {
                const int row = mwl + i * 16 + qr * 4 + r;
                Ce[row * 128 + col] = (f16)(acc[i][j][r] + bv);
            }
        }
    }
    __syncthreads();
#pragma unroll
    for (int r = 0; r < 8; r++) {
        const int f = r * 256 + tid;
        const int row = f >> 4, c16 = f & 15;
        uint4 v = *(const uint4*)&Ce[row * 128 + c16 * 8];
        *(uint4*)(Cz + (size_t)(m0 + row) * 256 + n0 + c16 * 8) = v;
    }
}

// ---------------------------------------------------------------------------
// Per (b,q): cc[i,j] = sum_e ac[b,i,e]*other[b,j,e] via MFMA (f16 in, f32 acc),
// fragments read directly from global. Then both softmaxes, wave-parallel:
// 4-way partial max/sum per row & column (16-iter loops, all 256 threads),
// online combine (sum rescaled by exp(pm - M)), then coalesced f16 writes.
// Outputs (f16): aT[q][b][j][i] = softmax_i(cc)[i,j]  (transposed!)
//                oP[q][b][i][j] = softmax_j(cc)[i,j]  (row-major)
__global__ __launch_bounds__(256) void cc_softmax(const f16* __restrict__ ac,
                                                  const f16* __restrict__ proj1,
                                                  const f16* __restrict__ proj2,
                                                  f16* __restrict__ aT,
                                                  f16* __restrict__ oP) {
    const int b = blockIdx.x, q = blockIdx.y;
    const f16* __restrict__ A = ac + (size_t)b * Ssz * Dsz;
    const f16* __restrict__ Bp = (q ? proj2 : proj1) + (size_t)b * Ssz * Dsz;
    __shared__ float sc[64][65];
    __shared__ float pm[4][64], ps[4][64], qm[4][64], qs[4][64];
    __shared__ float CM[64], CI[64], RM[64], RI[64];
    const int tid = threadIdx.x;
    const int lane = tid & 63, w = tid >> 6;
    const int lr = lane & 15;   // row/col within 16-tile (A row, B col)
    const int lk = lane >> 4;   // k-quarter: k = 8*lk + 0..7 within K=32 step

    f32x4 acc[4];
#pragma unroll
    for (int j = 0; j < 4; j++) acc[j] = (f32x4){0.f, 0.f, 0.f, 0.f};

    const f16* __restrict__ Arow = A + (size_t)(w * 16 + lr) * Dsz + lk * 8;
    for (int ks = 0; ks < 8; ks++) {  // K=256 in steps of 32
        f16x8v af = *(const f16x8v*)(Arow + ks * 32);
        f16x8v bf[4];
#pragma unroll
        for (int j = 0; j < 4; j++)
            bf[j] = *(const f16x8v*)(Bp + (size_t)(j * 16 + lr) * Dsz + ks * 32 + lk * 8);
#pragma unroll
        for (int j = 0; j < 4; j++)
            acc[j] = __builtin_amdgcn_mfma_f32_16x16x32_f16(af, bf[j], acc[j], 0, 0, 0);
    }
    // C/D layout: col = lane&15, row = (lane>>4)*4 + r
#pragma unroll
    for (int j = 0; j < 4; j++)
#pragma unroll
        for (int r = 0; r < 4; r++) sc[w * 16 + lk * 4 + r][j * 16 + lr] = acc[j][r];
    __syncthreads();

    const int lid = tid & 63, qa = tid >> 6;
    float m1 = -1e30f, m2 = -1e30f;
#pragma unroll
    for (int it = 0; it < 16; it++) {
        m1 = fmaxf(m1, sc[qa * 16 + it][lid]);  // column lid (reduce over i)
        m2 = fmaxf(m2, sc[lid][qa * 16 + it]);  // row lid (reduce over j)
    }
    float s1 = 0.f, s2 = 0.f;
#pragma unroll
    for (int it = 0; it < 16; it++) {
        s1 += __expf(sc[qa * 16 + it][lid] - m1);
        s2 += __expf(sc[lid][qa * 16 + it] - m2);
    }
    pm[qa][lid] = m1; ps[qa][lid] = s1;
    qm[qa][lid] = m2; qs[qa][lid] = s2;
    __syncthreads();
    if (tid < 128) {
        const int x = tid & 63;
        const bool col = tid < 64;
        float M = -1e30f;
#pragma unroll
        for (int u = 0; u < 4; u++) M = fmaxf(M, col ? pm[u][x] : qm[u][x]);
        float S = 0.f;
#pragma unroll
        for (int u = 0; u < 4; u++)
            S += (col ? ps[u][x] : qs[u][x]) * __expf((col ? pm[u][x] : qm[u][x]) - M);
        if (col) { CM[x] = M; CI[x] = 1.f / S; }
        else     { RM[x] = M; RI[x] = 1.f / S; }
    }
    __syncthreads();
    f16* __restrict__ apT = aT + (size_t)(q * Bsz + b) * 4096;
    f16* __restrict__ opR = oP + (size_t)(q * Bsz + b) * 4096;
#pragma unroll
    for (int it = 0; it < 16; it++) {
        const int i = qa * 16 + it;
        opR[i * 64 + lid] = (f16)(__expf(sc[i][lid] - RM[i]) * RI[i]);
        apT[i * 64 + lid] = (f16)(__expf(sc[lid][i] - CM[i]) * CI[i]);
    }
}

// ---------------------------------------------------------------------------
// Fused tail: G GEMMs + attention contraction + bias + LayerNorm + ReLU.
// Phase G: wave w computes term w: G_w[o][t] = sum_d Wchunk[o,d]*X[t,d]
//   (term = q*2+part; part0: X=anchor(proj0); part1: X=other_q(proj1/2);
//    Wchunk = Wbh[:, q*512+part*256 : +256]) -> swizzled LDS (no global G).
// Phase LN: h[b,s,o] = sum_term( sum_k A_term[s,k]*G_term[o,k] + G_term[o,s] ) + bb[o]
//   term0: A=aT(q0); term1: A=oP(q0); term2: A=aT(q1); term3: A=oP(q1)
// Wave w owns rows s in [16w,16w+16) x all 64 o; LN via 16-lane shfl reduce.
// Gs swizzle: element (o,t) at unit su = o*8 + ((t>>3) ^ (o&7)), offset t&7.
__global__ __launch_bounds__(256) void fused_tail(const f16* __restrict__ proj,
                                                  const f16* __restrict__ Wbh,
                                                  const f16* __restrict__ aT,
                                                  const f16* __restrict__ oP,
                                                  const float* __restrict__ bb,
                                                  const float* __restrict__ gamma,
                                                  const float* __restrict__ beta,
                                                  float* __restrict__ out) {
    const int b = blockIdx.x;
    const int tid = threadIdx.x, lane = tid & 63, w = tid >> 6;
    const int lr = lane & 15, lk = lane >> 4;

    __shared__ __align__(16) f16 Gs[4][4096];

    // ---- G phase: wave w computes its term, K=256, direct-global fragments
    {
        const int q = w >> 1, part = w & 1;
        const int z = part ? (1 + q) : 0;
        const f16* __restrict__ X = proj + ((size_t)z * MROWS + b * 64) * 256;  // [t][256]
        const f16* __restrict__ Wc = Wbh + q * 512 + part * 256;                // rows stride 1024
        f32x4 gacc[4][4];
#pragma unroll
        for (int i = 0; i < 4; i++)
#pragma unroll
            for (int j = 0; j < 4; j++) gacc[i][j] = (f32x4){0.f, 0.f, 0.f, 0.f};
        for (int ks = 0; ks < 8; ks++) {
            f16x8v af[4], bf[4];
#pragma unroll
            for (int mi = 0; mi < 4; mi++)
                af[mi] = *(const f16x8v*)(Wc + (size_t)(mi * 16 + lr) * FIN + ks * 32 + lk * 8);
#pragma unroll
            for (int nj = 0; nj < 4; nj++)
                bf[nj] = *(const f16x8v*)(X + (size_t)(nj * 16 + lr) * 256 + ks * 32 + lk * 8);
#pragma unroll
            for (int mi = 0; mi < 4; mi++)
#pragma unroll
                for (int nj = 0; nj < 4; nj++)
                    gacc[mi][nj] = __builtin_amdgcn_mfma_f32_16x16x32_f16(af[mi], bf[nj], gacc[mi][nj], 0, 0, 0);
        }
        // scatter into swizzled Gs[w]
#pragma unroll
        for (int mi = 0; mi < 4; mi++)
#pragma unroll
            for (int nj = 0; nj < 4; nj++)
#pragma unroll
                for (int r = 0; r < 4; r++) {
                    const int o = mi * 16 + lk * 4 + r;
                    const int t = nj * 16 + lr;
                    Gs[w][(o * 8 + ((t >> 3) ^ (o & 7))) * 8 + (t & 7)] = (f16)gacc[mi][nj][r];
                }
    }
    __syncthreads();

    // ---- attn + LN phase
    f32x4 acc[4];
#pragma unroll
    for (int j = 0; j < 4; j++) acc[j] = (f32x4){0.f, 0.f, 0.f, 0.f};

#pragma unroll
    for (int term = 0; term < 4; term++) {
        const int q = term >> 1;
        const f16* __restrict__ Abase =
            ((term & 1) ? oP : aT) + ((size_t)(q * Bsz + b)) * 4096;
#pragma unroll
        for (int kh = 0; kh < 2; kh++) {
            f16x8v af = *(const f16x8v*)(Abase + (size_t)(w * 16 + lr) * 64 + kh * 32 + lk * 8);
#pragma unroll
            for (int jf = 0; jf < 4; jf++) {
                const int o = jf * 16 + lr;
                const int su = o * 8 + ((kh * 4 + lk) ^ (o & 7));
                f16x8v bf = *(const f16x8v*)&Gs[term][su * 8];
                acc[jf] = __builtin_amdgcn_mfma_f32_16x16x32_f16(af, bf, acc[jf], 0, 0, 0);
            }
        }
    }

    float bbv[4], gv[4], bv2[4];
#pragma unroll
    for (int jf = 0; jf < 4; jf++) {
        const int o = jf * 16 + lr;
        bbv[jf] = bb[o];
        gv[jf] = gamma[o];
        bv2[jf] = beta[o];
    }
#pragma unroll
    for (int r = 0; r < 4; r++) {
        const int s = w * 16 + lk * 4 + r;
        float h[4];
        float s1 = 0.f, s2 = 0.f;
#pragma unroll
        for (int jf = 0; jf < 4; jf++) {
            const int o = jf * 16 + lr;
            float resid = 0.f;
#pragma unroll
            for (int term = 0; term < 4; term++) {
                const int su = o * 8 + ((s >> 3) ^ (o & 7));
                resid += (float)Gs[term][su * 8 + (s & 7)];
            }
            h[jf] = acc[jf][r] + resid + bbv[jf];
            s1 += h[jf];
            s2 += h[jf] * h[jf];
        }
#pragma unroll
        for (int m = 1; m < 16; m <<= 1) {
            s1 += __shfl_xor(s1, m);
            s2 += __shfl_xor(s2, m);
        }
        const float mu = s1 * (1.f / 64.f);
        const float inv = rsqrtf(s2 * (1.f / 64.f) - mu * mu + 1e-5f);
#pragma unroll
        for (int jf = 0; jf < 4; jf++) {
            const float v = (h[jf] - mu) * inv * gv[jf] + bv2[jf];
            out[(size_t)(b * 64 + s) * 64 + jf * 16 + lr] = fmaxf(v, 0.f);
        }
    }
}

extern "C" void kernel_launch(void* const* d_in, const int* in_sizes, int n_in,
                              void* d_out, int out_size, void* d_ws, size_t ws_size,
                              hipStream_t stream) {
    const float* latent0 = (const float*)d_in[0];
    const float* Wp0 = (const float*)d_in[1];
    const float* bp0 = (const float*)d_in[2];
    const float* latent1 = (const float*)d_in[3];
    const float* Wp1 = (const float*)d_in[4];
    const float* bp1 = (const float*)d_in[5];
    const float* latent2 = (const float*)d_in[6];
    const float* Wp2 = (const float*)d_in[7];
    const float* bp2 = (const float*)d_in[8];
    const float* corr = (const float*)d_in[9];
    const float* Wb = (const float*)d_in[10];
    const float* bb = (const float*)d_in[11];
    const float* gamma = (const float*)d_in[12];
    const float* beta = (const float*)d_in[13];

    char* ws = (char*)d_ws;
    f16* proj_h = (f16*)ws;                               // 3 * 16 MB
    f16* ac_h = (f16*)(ws + 48ull * 1024 * 1024);         // 16 MB
    f16* aT = (f16*)(ws + 64ull * 1024 * 1024);           // 8 MB  [2][512][64][64]
    f16* oP = (f16*)(ws + 72ull * 1024 * 1024);           // 8 MB  [2][512][64][64]
    f16* Wph = (f16*)(ws + 160ull * 1024 * 1024);         // 1.125 MB
    f16* corrT = (f16*)(ws + 162ull * 1024 * 1024);       // 128 KB
    f16* Wbh = (f16*)(ws + 162ull * 1024 * 1024 + 128ull * 1024);  // 128 KB

    float* out = (float*)d_out;
    dim3 blk(256);

    // pre-convert weights
    prep<<<2304, blk, 0, stream>>>(Wp0, Wp1, Wp2, corr, Wb, Wph, corrT, Wbh);

    // projections: proj_h[z] = latent_z @ Wp_z^T + bp_z  (fp16 MFMA, counted-vmcnt dbuf)
    mfma_gemm<false, true><<<dim3(2, 256, 3), blk, 0, stream>>>(
        latent0, latent1, latent2, (const f16*)nullptr, Wph, bp0, bp1, bp2, proj_h, Esz);

    // ac = proj0 @ corr  (B = corrT [e][d] f16)
    mfma_gemm<true, false><<<dim3(2, 256, 1), blk, 0, stream>>>(
        (const float*)nullptr, (const float*)nullptr, (const float*)nullptr, proj_h,
        corrT, (const float*)nullptr, (const float*)nullptr, (const float*)nullptr,
        ac_h, Dsz);

    const f16* proj1_h = proj_h + (size_t)MROWS * 256;
    const f16* proj2_h = proj_h + 2ull * MROWS * 256;

    // cc (MFMA) + both softmaxes -> aT (transposed) and oP (row-major), f16
    cc_softmax<<<dim3(Bsz, 2), blk, 0, stream>>>(ac_h, proj1_h, proj2_h, aT, oP);

    // fused G GEMMs + attention contraction + bias + LayerNorm + ReLU
    fused_tail<<<Bsz, blk, 0, stream>>>(proj_h, Wbh, aT, oP, bb, gamma, beta, out);

    (void)in_sizes; (void)n_in; (void)out_size; (void)ws_size;
}

// Round 7
// 383.686 us; speedup vs baseline: 1.1090x; 1.0454x over previous
//
#include <hip/hip_runtime.h>
#include <hip/hip_bf16.h>
#include <stdint.h>

#define Bsz 512
#define Ssz 64
#define Esz 768
#define Dsz 256
#define MROWS (Bsz * Ssz)   // 32768
#define FIN 1024

typedef _Float16 f16;
typedef f16 f16x4 __attribute__((ext_vector_type(4)));
typedef f16 f16x8v __attribute__((ext_vector_type(8)));
typedef float f32x4 __attribute__((ext_vector_type(4)));

// async 16B/lane global->LDS copy. LDS dest = wave-uniform base + lane*16.
__device__ __forceinline__ void async_copy16(const void* g, void* l) {
    __builtin_amdgcn_global_load_lds((const __attribute__((address_space(1))) uint32_t*)g,
                                     (__attribute__((address_space(3))) uint32_t*)l, 16, 0, 0);
}

// ---------------------------------------------------------------------------
// prep: Wp (3x[256][768] f32) -> f16; corr [256][256] f32 -> corrT f16 [e][d];
//       Wb [64][1024] f32 -> f16 (for the G GEMMs)
__global__ __launch_bounds__(256) void prep(const float* __restrict__ Wp0,
                                            const float* __restrict__ Wp1,
                                            const float* __restrict__ Wp2,
                                            const float* __restrict__ corr,
                                            const float* __restrict__ Wb,
                                            f16* __restrict__ Wph,
                                            f16* __restrict__ corrT,
                                            f16* __restrict__ Wbh) {
    const int t = blockIdx.x * 256 + threadIdx.x;
    if (t < 3 * 196608) {
        const int z = t / 196608, i = t % 196608;
        const float* W = (z == 0) ? Wp0 : (z == 1) ? Wp1 : Wp2;
        Wph[(size_t)z * 196608 + i] = (f16)W[i];
    }
    if (t < 65536) {
        const int d = t >> 8, e = t & 255;
        corrT[e * 256 + d] = (f16)corr[d * 256 + e];
        Wbh[t] = (f16)Wb[t];
    }
}

// ---------------------------------------------------------------------------
// MFMA GEMM: C[m,n] = sum_k A[m,k] * B[n,k]  (B [N=256][K] row-major, f16)
// FULL-N tile 128x256xBK32, 256 threads = 4 waves, wave owns 64x128.
// Each A byte traverses the CU staging path ONCE (was twice with 128x128);
// 32 MFMA per barrier-pair (was 16). Counted-vmcnt double-buffer as R5:
// stage(t+1) -> s_waitcnt vmcnt(N) (tile t done, t+1 in flight) -> s_barrier
// -> compute -> s_barrier. No registers near barriers (pure global_load_lds).
// Swizzles (same involution at stage-source and fragment-read):
//   A_F32: unit(row,c)   at row*8 + (c ^ (row&7)),            c = k/4 (0..7)
//   A_F16: unit(row,u)   at row*4 + (u ^ (row&3) ^ ((row>>2)&3)), u = k/8
//   B f16: unit(row,u)   same as A_F16 (256 rows)
// Epilogue: 128x256 f16 = 4096 uint4 units / 256 threads = 16 iters (NOT 32 —
// R6's 32 caused LDS OOB reads + global OOB writes => queue kill).
template <bool A_F16, bool BIAS>
__global__ __launch_bounds__(256, 2) void mfma_gemm(
    const float* __restrict__ A32a, const float* __restrict__ A32b,
    const float* __restrict__ A32c, const f16* __restrict__ A16,
    const f16* __restrict__ Bh, const float* __restrict__ biasA,
    const float* __restrict__ biasB, const float* __restrict__ biasC,
    f16* __restrict__ Ch, int K) {
    constexpr int ABYTES = A_F16 ? 8192 : 16384;  // A tile bytes per buffer
    constexpr int BBYTES = 16384;                 // B tile: 256 rows x 64 B
    constexpr int BUF = ABYTES + BBYTES;
    __shared__ __align__(16) char smem[65536];    // 2*BUF <= 64 KB; epilogue 64 KB

    const int tid = threadIdx.x;
    const int m0 = blockIdx.y * 128;
    const int z = blockIdx.z;
    const float* A32 = (z == 0) ? A32a : (z == 1) ? A32b : A32c;
    const float* bias = (z == 0) ? biasA : (z == 1) ? biasB : biasC;
    const f16* Bz = Bh + (size_t)z * 256 * K;
    f16* Cz = Ch + (size_t)z * MROWS * 256;

    const int lane = tid & 63;
    const int w = tid >> 6;
    const int lr = lane & 15;
    const int lk = lane >> 4;
    const int ma = (w >> 1) * 4;  // wave's first m-sub (of 8)
    const int nb = (w & 1) * 8;   // wave's first n-sub (of 16)

    f32x4 acc[4][8];
#pragma unroll
    for (int i = 0; i < 4; i++)
#pragma unroll
        for (int j = 0; j < 8; j++) acc[i][j] = (f32x4){0.f, 0.f, 0.f, 0.f};

    auto stage = [&](int buf, int k0) {
        char* base = smem + buf * BUF;
        // A tile (f32: 1024 units, 4 insts/wave; f16: 512 units, 2 insts/wave)
#pragma unroll
        for (int i = 0; i < (A_F16 ? 2 : 4); i++) {
            const int Ub = (w * (A_F16 ? 2 : 4) + i) * 64;
            const int U = Ub + lane;
            if constexpr (A_F16) {
                const int row = U >> 2, u = (U & 3) ^ (row & 3) ^ ((row >> 2) & 3);
                async_copy16(A16 + (size_t)(m0 + row) * K + k0 + u * 8, base + Ub * 16);
            } else {
                const int row = U >> 3, c = (U & 7) ^ (row & 7);
                async_copy16(A32 + (size_t)(m0 + row) * K + k0 + c * 4, base + Ub * 16);
            }
        }
        // B tile (1024 units, 4 insts/wave), rows are absolute n (0..255)
#pragma unroll
        for (int i = 0; i < 4; i++) {
            const int Ub = (w * 4 + i) * 64;
            const int U = Ub + lane;
            const int row = U >> 2, u = (U & 3) ^ (row & 3) ^ ((row >> 2) & 3);
            async_copy16(Bz + (size_t)row * K + k0 + u * 8, base + ABYTES + Ub * 16);
        }
    };

    stage(0, 0);
    int cur = 0;
    const int NT = K >> 5;
    for (int t = 0; t < NT; t++) {
        if (t + 1 < NT) {
            stage(cur ^ 1, (t + 1) << 5);  // next tile: in flight through compute
            if constexpr (A_F16) {
                asm volatile("s_waitcnt vmcnt(6)" ::: "memory");  // tile t landed
            } else {
                asm volatile("s_waitcnt vmcnt(8)" ::: "memory");
            }
        } else {
            asm volatile("s_waitcnt vmcnt(0)" ::: "memory");
        }
        __builtin_amdgcn_sched_barrier(0);
        asm volatile("s_barrier" ::: "memory");  // raw: no vmcnt(0) auto-drain
        __builtin_amdgcn_sched_barrier(0);

        const char* base = smem + cur * BUF;
        const f16* Af16L = (const f16*)base;
        const float* Af32L = (const float*)base;
        const f16* BfL = (const f16*)(base + ABYTES);
        const int usw = lk ^ (lr & 3) ^ ((lr >> 2) & 3);  // lane-only f16 swizzle
        f16x8v af[4], bf[8];
#pragma unroll
        for (int i = 0; i < 4; i++) {
            const int row = (ma + i) * 16 + lr;
            if constexpr (A_F16) {
                af[i] = *(const f16x8v*)&Af16L[(row * 4 + usw) * 8];
            } else {
                const int c0 = (2 * lk) ^ (lr & 7);
                const int c1 = c0 ^ 1;
                const float4 v1 = *(const float4*)&Af32L[(row * 8 + c0) * 4];
                const float4 v2 = *(const float4*)&Af32L[(row * 8 + c1) * 4];
                f16x8v h;
                h[0] = (f16)v1.x; h[1] = (f16)v1.y; h[2] = (f16)v1.z; h[3] = (f16)v1.w;
                h[4] = (f16)v2.x; h[5] = (f16)v2.y; h[6] = (f16)v2.z; h[7] = (f16)v2.w;
                af[i] = h;
            }
        }
#pragma unroll
        for (int j = 0; j < 8; j++) {
            const int row = (nb + j) * 16 + lr;
            bf[j] = *(const f16x8v*)&BfL[(row * 4 + usw) * 8];
        }
#pragma unroll
        for (int i = 0; i < 4; i++)
#pragma unroll
            for (int j = 0; j < 8; j++)
                acc[i][j] = __builtin_amdgcn_mfma_f32_16x16x32_f16(af[i], bf[j], acc[i][j], 0, 0, 0);

        __builtin_amdgcn_sched_barrier(0);
        asm volatile("s_barrier" ::: "memory");  // all waves done reading buf cur
        cur ^= 1;
    }

    // epilogue through LDS for coalesced stores. 128x256 f16 = 64 KB.
    f16* Ce = (f16*)smem;
    const int cr = lane & 15, qr = lane >> 4;
    const int mwl = (w >> 1) * 64;
    const int nwl = (w & 1) * 128;
#pragma unroll
    for (int i = 0; i < 4; i++) {
#pragma unroll
        for (int j = 0; j < 8; j++) {
            const int col = nwl + j * 16 + cr;
            const float bv = BIAS ? bias[col] : 0.f;
#pragma unroll
            for (int r = 0; r < 4; r++) {
                const int row = mwl + i * 16 + qr * 4 + r;
                Ce[row * 256 + col] = (f16)(acc[i][j][r] + bv);
            }
        }
    }
    __syncthreads();
#pragma unroll
    for (int r = 0; r < 16; r++) {  // 4096 units / 256 threads = 16 (FIX: was 32)
        const int f = r * 256 + tid;
        const int row = f >> 5, c16 = f & 31;
        uint4 v = *(const uint4*)&Ce[row * 256 + c16 * 8];
        *(uint4*)(Cz + (size_t)(m0 + row) * 256 + c16 * 8) = v;
    }
}

// ---------------------------------------------------------------------------
// Per (b,q): cc[i,j] = sum_e ac[b,i,e]*other[b,j,e] via MFMA, operands staged
// coalesced into LDS (global_load_lds, swizzled: unit(row,u) at
// row*32 + (u ^ (row&15)), u = k/8, 32 units/row). Softmax buffers alias the
// staged tiles after a barrier. Wave-parallel 4-way partial max/sum.
// Outputs (f16): aT[q][b][j][i] = softmax_i(cc)[i,j]  (transposed!)
//                oP[q][b][i][j] = softmax_j(cc)[i,j]  (row-major)
__global__ __launch_bounds__(256) void cc_softmax(const f16* __restrict__ ac,
                                                  const f16* __restrict__ proj1,
                                                  const f16* __restrict__ proj2,
                                                  f16* __restrict__ aT,
                                                  f16* __restrict__ oP) {
    const int b = blockIdx.x, q = blockIdx.y;
    const f16* __restrict__ Ag = ac + (size_t)b * Ssz * Dsz;
    const f16* __restrict__ Bg = (q ? proj2 : proj1) + (size_t)b * Ssz * Dsz;
    __shared__ __align__(16) char csmem[65536];
    f16* As = (f16*)csmem;               // 32 KB: 64 rows x 32 units
    f16* Bs = (f16*)(csmem + 32768);     // 32 KB
    float* sc = (float*)csmem;           // alias: [64][65] after compute barrier
    float* pm = (float*)(csmem + 32768); // alias: partials [4][64] x4 + finals
    float* ps = pm + 256;
    float* qm = ps + 256;
    float* qs = qm + 256;
    float* CM = qs + 256;
    float* CI = CM + 64;
    float* RM = CI + 64;
    float* RI = RM + 64;

    const int tid = threadIdx.x;
    const int lane = tid & 63, w = tid >> 6;
    const int lr = lane & 15;
    const int lk = lane >> 4;

    // stage both 32 KB tiles, coalesced + swizzled
#pragma unroll
    for (int r = 0; r < 8; r++) {
        const int Ub = (w * 8 + r) * 64;
        const int U = Ub + lane;
        const int row = U >> 5, u0 = U & 31;
        const int gu = u0 ^ (row & 15);
        async_copy16(Ag + (size_t)row * 256 + gu * 8, csmem + Ub * 16);
        async_copy16(Bg + (size_t)row * 256 + gu * 8, csmem + 32768 + Ub * 16);
    }
    __syncthreads();

    f32x4 acc[4];
#pragma unroll
    for (int j = 0; j < 4; j++) acc[j] = (f32x4){0.f, 0.f, 0.f, 0.f};

    for (int ks = 0; ks < 8; ks++) {  // K=256 in steps of 32
        const int arow = w * 16 + lr;
        f16x8v af = *(const f16x8v*)&As[(arow * 32 + ((ks * 4 + lk) ^ lr)) * 8];
        f16x8v bf[4];
#pragma unroll
        for (int j = 0; j < 4; j++) {
            const int brow = j * 16 + lr;
            bf[j] = *(const f16x8v*)&Bs[(brow * 32 + ((ks * 4 + lk) ^ lr)) * 8];
        }
#pragma unroll
        for (int j = 0; j < 4; j++)
            acc[j] = __builtin_amdgcn_mfma_f32_16x16x32_f16(af, bf[j], acc[j], 0, 0, 0);
    }
    __syncthreads();  // all waves done reading As/Bs -> safe to alias
    // C/D layout: col = lane&15, row = (lane>>4)*4 + r
#pragma unroll
    for (int j = 0; j < 4; j++)
#pragma unroll
        for (int r = 0; r < 4; r++) sc[(w * 16 + lk * 4 + r) * 65 + j * 16 + lr] = acc[j][r];
    __syncthreads();

    const int lid = tid & 63, qa = tid >> 6;
    float m1 = -1e30f, m2 = -1e30f;
#pragma unroll
    for (int it = 0; it < 16; it++) {
        m1 = fmaxf(m1, sc[(qa * 16 + it) * 65 + lid]);  // column lid (over i)
        m2 = fmaxf(m2, sc[lid * 65 + qa * 16 + it]);    // row lid (over j)
    }
    float s1 = 0.f, s2 = 0.f;
#pragma unroll
    for (int it = 0; it < 16; it++) {
        s1 += __expf(sc[(qa * 16 + it) * 65 + lid] - m1);
        s2 += __expf(sc[lid * 65 + qa * 16 + it] - m2);
    }
    pm[qa * 64 + lid] = m1; ps[qa * 64 + lid] = s1;
    qm[qa * 64 + lid] = m2; qs[qa * 64 + lid] = s2;
    __syncthreads();
    if (tid < 128) {
        const int x = tid & 63;
        const bool col = tid < 64;
        float M = -1e30f;
#pragma unroll
        for (int u = 0; u < 4; u++) M = fmaxf(M, col ? pm[u * 64 + x] : qm[u * 64 + x]);
        float S = 0.f;
#pragma unroll
        for (int u = 0; u < 4; u++)
            S += (col ? ps[u * 64 + x] : qs[u * 64 + x]) *
                 __expf((col ? pm[u * 64 + x] : qm[u * 64 + x]) - M);
        if (col) { CM[x] = M; CI[x] = 1.f / S; }
        else     { RM[x] = M; RI[x] = 1.f / S; }
    }
    __syncthreads();
    f16* __restrict__ apT = aT + (size_t)(q * Bsz + b) * 4096;
    f16* __restrict__ opR = oP + (size_t)(q * Bsz + b) * 4096;
#pragma unroll
    for (int it = 0; it < 16; it++) {
        const int i = qa * 16 + it;
        opR[i * 64 + lid] = (f16)(__expf(sc[i * 65 + lid] - RM[i]) * RI[i]);
        apT[i * 64 + lid] = (f16)(__expf(sc[lid * 65 + i] - CM[i]) * CI[i]);
    }
}

// ---------------------------------------------------------------------------
// Fused tail: G GEMMs + attention contraction + bias + LayerNorm + ReLU.
// Phase G: wave w computes term w, with SWAPPED operands (A=X rows, B=Wc rows)
// so the C/D fragment holds 4 consecutive t per lane -> packed 8B ds_write.
// Gs layout unchanged: element (o,t) at unit o*8 + ((t>>3)^(o&7)), offset t&7.
// Phase LN: h[b,s,o] = sum_term( sum_k A_term[s,k]*G_term[o,k] + G_term[o,s] ) + bb[o]
__global__ __launch_bounds__(256) void fused_tail(const f16* __restrict__ proj,
                                                  const f16* __restrict__ Wbh,
                                                  const f16* __restrict__ aT,
                                                  const f16* __restrict__ oP,
                                                  const float* __restrict__ bb,
                                                  const float* __restrict__ gamma,
                                                  const float* __restrict__ beta,
                                                  float* __restrict__ out) {
    const int b = blockIdx.x;
    const int tid = threadIdx.x, lane = tid & 63, w = tid >> 6;
    const int lr = lane & 15, lk = lane >> 4;

    __shared__ __align__(16) f16 Gs[4][4096];

    // ---- G phase: wave w computes its term, K=256, direct-global fragments
    {
        const int q = w >> 1, part = w & 1;
        const int z = part ? (1 + q) : 0;
        const f16* __restrict__ X = proj + ((size_t)z * MROWS + b * 64) * 256;  // [t][256]
        const f16* __restrict__ Wc = Wbh + q * 512 + part * 256;                // rows stride 1024
        f32x4 gacc[4][4];  // [t-frag][o-frag]
#pragma unroll
        for (int i = 0; i < 4; i++)
#pragma unroll
            for (int j = 0; j < 4; j++) gacc[i][j] = (f32x4){0.f, 0.f, 0.f, 0.f};
        for (int ks = 0; ks < 8; ks++) {
            f16x8v xf[4], wf[4];
#pragma unroll
            for (int tt = 0; tt < 4; tt++)
                xf[tt] = *(const f16x8v*)(X + (size_t)(tt * 16 + lr) * 256 + ks * 32 + lk * 8);
#pragma unroll
            for (int oo = 0; oo < 4; oo++)
                wf[oo] = *(const f16x8v*)(Wc + (size_t)(oo * 16 + lr) * FIN + ks * 32 + lk * 8);
#pragma unroll
            for (int tt = 0; tt < 4; tt++)
#pragma unroll
                for (int oo = 0; oo < 4; oo++)
                    gacc[tt][oo] = __builtin_amdgcn_mfma_f32_16x16x32_f16(xf[tt], wf[oo], gacc[tt][oo], 0, 0, 0);
        }
        // packed scatter: lane holds t = tt*16 + lk*4 + r (r=0..3), o = oo*16 + lr
#pragma unroll
        for (int tt = 0; tt < 4; tt++)
#pragma unroll
            for (int oo = 0; oo < 4; oo++) {
                const int o = oo * 16 + lr;
                const int su = o * 8 + ((tt * 2 + (lk >> 1)) ^ (o & 7));
                f16x4 pk;
                pk[0] = (f16)gacc[tt][oo][0];
                pk[1] = (f16)gacc[tt][oo][1];
                pk[2] = (f16)gacc[tt][oo][2];
                pk[3] = (f16)gacc[tt][oo][3];
                *(f16x4*)&Gs[w][su * 8 + (lk & 1) * 4] = pk;
            }
    }
    __syncthreads();

    // ---- attn + LN phase
    f32x4 acc[4];
#pragma unroll
    for (int j = 0; j < 4; j++) acc[j] = (f32x4){0.f, 0.f, 0.f, 0.f};

#pragma unroll
    for (int term = 0; term < 4; term++) {
        const int q = term >> 1;
        const f16* __restrict__ Abase =
            ((term & 1) ? oP : aT) + ((size_t)(q * Bsz + b)) * 4096;
#pragma unroll
        for (int kh = 0; kh < 2; kh++) {
            f16x8v af = *(const f16x8v*)(Abase + (size_t)(w * 16 + lr) * 64 + kh * 32 + lk * 8);
#pragma unroll
            for (int jf = 0; jf < 4; jf++) {
                const int o = jf * 16 + lr;
                const int su = o * 8 + ((kh * 4 + lk) ^ (o & 7));
                f16x8v bf = *(const f16x8v*)&Gs[term][su * 8];
                acc[jf] = __builtin_amdgcn_mfma_f32_16x16x32_f16(af, bf, acc[jf], 0, 0, 0);
            }
        }
    }

    float bbv[4], gv[4], bv2[4];
#pragma unroll
    for (int jf = 0; jf < 4; jf++) {
        const int o = jf * 16 + lr;
        bbv[jf] = bb[o];
        gv[jf] = gamma[o];
        bv2[jf] = beta[o];
    }
#pragma unroll
    for (int r = 0; r < 4; r++) {
        const int s = w * 16 + lk * 4 + r;
        float h[4];
        float s1 = 0.f, s2 = 0.f;
#pragma unroll
        for (int jf = 0; jf < 4; jf++) {
            const int o = jf * 16 + lr;
            float resid = 0.f;
#pragma unroll
            for (int term = 0; term < 4; term++) {
                const int su = o * 8 + ((s >> 3) ^ (o & 7));
                resid += (float)Gs[term][su * 8 + (s & 7)];
            }
            h[jf] = acc[jf][r] + resid + bbv[jf];
            s1 += h[jf];
            s2 += h[jf] * h[jf];
        }
#pragma unroll
        for (int m = 1; m < 16; m <<= 1) {
            s1 += __shfl_xor(s1, m);
            s2 += __shfl_xor(s2, m);
        }
        const float mu = s1 * (1.f / 64.f);
        const float inv = rsqrtf(s2 * (1.f / 64.f) - mu * mu + 1e-5f);
#pragma unroll
        for (int jf = 0; jf < 4; jf++) {
            const float v = (h[jf] - mu) * inv * gv[jf] + bv2[jf];
            out[(size_t)(b * 64 + s) * 64 + jf * 16 + lr] = fmaxf(v, 0.f);
        }
    }
}

extern "C" void kernel_launch(void* const* d_in, const int* in_sizes, int n_in,
                              void* d_out, int out_size, void* d_ws, size_t ws_size,
                              hipStream_t stream) {
    const float* latent0 = (const float*)d_in[0];
    const float* Wp0 = (const float*)d_in[1];
    const float* bp0 = (const float*)d_in[2];
    const float* latent1 = (const float*)d_in[3];
    const float* Wp1 = (const float*)d_in[4];
    const float* bp1 = (const float*)d_in[5];
    const float* latent2 = (const float*)d_in[6];
    const float* Wp2 = (const float*)d_in[7];
    const float* bp2 = (const float*)d_in[8];
    const float* corr = (const float*)d_in[9];
    const float* Wb = (const float*)d_in[10];
    const float* bb = (const float*)d_in[11];
    const float* gamma = (const float*)d_in[12];
    const float* beta = (const float*)d_in[13];

    char* ws = (char*)d_ws;
    f16* proj_h = (f16*)ws;                               // 3 * 16 MB
    f16* ac_h = (f16*)(ws + 48ull * 1024 * 1024);         // 16 MB
    f16* aT = (f16*)(ws + 64ull * 1024 * 1024);           // 8 MB  [2][512][64][64]
    f16* oP = (f16*)(ws + 72ull * 1024 * 1024);           // 8 MB  [2][512][64][64]
    f16* Wph = (f16*)(ws + 160ull * 1024 * 1024);         // 1.125 MB
    f16* corrT = (f16*)(ws + 162ull * 1024 * 1024);       // 128 KB
    f16* Wbh = (f16*)(ws + 162ull * 1024 * 1024 + 128ull * 1024);  // 128 KB

    float* out = (float*)d_out;
    dim3 blk(256);

    // pre-convert weights
    prep<<<2304, blk, 0, stream>>>(Wp0, Wp1, Wp2, corr, Wb, Wph, corrT, Wbh);

    // projections: proj_h[z] = latent_z @ Wp_z^T + bp_z  (full-N tile, counted-vmcnt dbuf)
    mfma_gemm<false, true><<<dim3(1, 256, 3), blk, 0, stream>>>(
        latent0, latent1, latent2, (const f16*)nullptr, Wph, bp0, bp1, bp2, proj_h, Esz);

    // ac = proj0 @ corr  (B = corrT [e][d] f16)
    mfma_gemm<true, false><<<dim3(1, 256, 1), blk, 0, stream>>>(
        (const float*)nullptr, (const float*)nullptr, (const float*)nullptr, proj_h,
        corrT, (const float*)nullptr, (const float*)nullptr, (const float*)nullptr,
        ac_h, Dsz);

    const f16* proj1_h = proj_h + (size_t)MROWS * 256;
    const f16* proj2_h = proj_h + 2ull * MROWS * 256;

    // cc (MFMA, LDS-staged operands) + both softmaxes -> aT, oP (f16)
    cc_softmax<<<dim3(Bsz, 2), blk, 0, stream>>>(ac_h, proj1_h, proj2_h, aT, oP);

    // fused G GEMMs (packed Gs writes) + attention contraction + LayerNorm + ReLU
    fused_tail<<<Bsz, blk, 0, stream>>>(proj_h, Wbh, aT, oP, bb, gamma, beta, out);

    (void)in_sizes; (void)n_in; (void)out_size; (void)ws_size;
}